// Round 1
// baseline (629.078 us; speedup 1.0000x reference)
//
#include <hip/hip_runtime.h>

#define SLOPE 0.2f

__device__ __forceinline__ float lrelu(float v){ return v > 0.0f ? v : SLOPE*v; }

// ConvTranspose1d(k=4, s=2, p=1), 128 in-ch, 128 out-ch, input length L (LDS),
// output length 2L (LDS). Thread tid = output channel, keeps full output row
// in registers. Derivation (JAX conv_transpose, lhs_dilation=2, pad=(2,2), IOH,
// no kernel flip):
//   t even: y[t] = sum_ci x[t/2-1]*w0 + x[t/2]*w2
//   t odd : y[t] = sum_ci x[(t-1)/2]*w1 + x[(t+1)/2]*w3
// i.e. x[i] contributes: w2 -> t=2i, w1 -> t=2i+1, w0 -> t=2i+2, w3 -> t=2i-1.
template<int L>
__device__ __forceinline__ void tconv128(const float* __restrict__ W,
                                         const float* __restrict__ bias,
                                         const float* __restrict__ in,
                                         float* __restrict__ out,
                                         int tid)
{
  float acc[2*L];
  {
    const float b = bias[tid];
    #pragma unroll
    for (int t=0;t<2*L;t++) acc[t] = b;
  }
  #pragma unroll 2
  for (int ci=0; ci<128; ci++) {
    const float4 w = *(const float4*)(W + (size_t)(ci*128+tid)*4);
    const float* xin = in + ci*L;
    #pragma unroll
    for (int i4=0;i4<L/4;i4++) {
      const float4 xq = *(const float4*)(xin + i4*4);
      const float xs[4] = {xq.x, xq.y, xq.z, xq.w};
      #pragma unroll
      for (int j=0;j<4;j++) {
        const int i = i4*4+j;
        const float xv = xs[j];
        acc[2*i]   += xv*w.z;
        acc[2*i+1] += xv*w.y;
        if (i+1 < L) acc[2*i+2] += xv*w.x;
        if (i >= 1)  acc[2*i-1] += xv*w.w;
      }
    }
  }
  #pragma unroll
  for (int t=0;t<2*L;t++) out[tid*(2*L)+t] = lrelu(acc[t]);
}

extern "C" __global__ __launch_bounds__(128)
void npg_fused(const float* __restrict__ x, const float* __restrict__ noise,
               const float* __restrict__ Wup, const float* __restrict__ bup,
               const float* __restrict__ Wd0, const float* __restrict__ bd0,
               const float* __restrict__ Wd1, const float* __restrict__ bd1,
               const float* __restrict__ Wd2, const float* __restrict__ bd2,
               const float* __restrict__ Wdo, const float* __restrict__ bdo,
               const float* __restrict__ Wc0, const float* __restrict__ bc0,
               const float* __restrict__ Wc1, const float* __restrict__ bc1,
               const float* __restrict__ Wc2, const float* __restrict__ bc2,
               const float* __restrict__ Wc3, const float* __restrict__ bc3,
               float* __restrict__ out)
{
  __shared__ float xrow[128];
  __shared__ float ha[128];
  __shared__ float hb[128];
  __shared__ float red[128];
  __shared__ float fr[128];
  __shared__ float bufA[128*32];   // 16 KB
  __shared__ float bufB[128*64];   // 32 KB
  __shared__ float sdecay;

  const int tid = threadIdx.x;
  const int row = blockIdx.x;

  xrow[tid] = x[row*128 + tid];
  __syncthreads();

  // ---- decay head: 3x (dense 128x128 + lrelu), dot with Wdo, sigmoid ----
  {
    float a = bd0[tid];
    #pragma unroll 4
    for (int i=0;i<128;i++) a += xrow[i]*Wd0[i*128+tid];
    ha[tid] = lrelu(a);
    __syncthreads();
    a = bd1[tid];
    #pragma unroll 4
    for (int i=0;i<128;i++) a += ha[i]*Wd1[i*128+tid];
    hb[tid] = lrelu(a);
    __syncthreads();
    a = bd2[tid];
    #pragma unroll 4
    for (int i=0;i<128;i++) a += hb[i]*Wd2[i*128+tid];
    red[tid] = lrelu(a) * Wdo[tid];
    __syncthreads();
    if (tid < 64) red[tid] += red[tid+64];
    __syncthreads();
    if (tid < 64) {
      float v = red[tid];
      #pragma unroll
      for (int off=32; off>0; off>>=1) v += __shfl_down(v, off, 64);
      if (tid == 0) {
        const float z = v + bdo[0];
        sdecay = 0.8f + 0.2f / (1.0f + expf(-z));
      }
    }
    __syncthreads();
  }

  // ---- up-linear: u0[ch=tid][s] = xf @ Wup + bup, -> bufA stride 8 ----
  {
    float a[8];
    #pragma unroll
    for (int s=0;s<8;s++) a[s] = bup[tid*8+s];
    #pragma unroll 2
    for (int i=0;i<128;i++) {
      const float xv = xrow[i];
      const float4 w0 = *(const float4*)(Wup + i*1024 + tid*8);
      const float4 w1 = *(const float4*)(Wup + i*1024 + tid*8 + 4);
      a[0] += xv*w0.x; a[1] += xv*w0.y; a[2] += xv*w0.z; a[3] += xv*w0.w;
      a[4] += xv*w1.x; a[5] += xv*w1.y; a[6] += xv*w1.z; a[7] += xv*w1.w;
    }
    #pragma unroll
    for (int s=0;s<8;s++) bufA[tid*8+s] = a[s];
    __syncthreads();
  }

  // ---- tconv chain: 8 -> 16 -> 32 -> 64 frames, 128 channels ----
  tconv128<8 >(Wc0, bc0, bufA, bufB, tid); __syncthreads();
  tconv128<16>(Wc1, bc1, bufB, bufA, tid); __syncthreads();
  tconv128<32>(Wc2, bc2, bufA, bufB, tid); __syncthreads();

  // ---- final tconv 128ch -> 1ch (length 64 -> 128), no lrelu, then square ----
  {
    const int t = tid;
    const bool even = ((t & 1) == 0);
    const int i  = t >> 1;                 // (t-1)/2 == t>>1 for odd t
    const int ia = even ? (i-1) : i;
    const int ib = even ? i : (i+1);
    const float ma = (ia >= 0) ? 1.0f : 0.0f;
    const float mb = (ib < 64) ? 1.0f : 0.0f;
    const int iac = (ia >= 0) ? ia : 0;
    const int ibc = (ib < 64) ? ib : 63;
    float a = bc3[0];
    #pragma unroll 2
    for (int ci=0;ci<128;ci++) {
      const float4 w = *(const float4*)(Wc3 + ci*4);
      const float wa = even ? w.x : w.y;
      const float wb = even ? w.z : w.w;
      a += (bufB[ci*64 + iac]*ma)*wa + (bufB[ci*64 + ibc]*mb)*wb;
    }
    fr[t] = a*a;
    __syncthreads();
  }

  // ---- weighted inclusive scan: v[t] = sum_{s<=t} decay^(t-s) * u[s] ----
  {
    float d = sdecay;
    #pragma unroll
    for (int o=1;o<128;o<<=1) {
      const float prev = (tid >= o) ? fr[tid-o] : 0.0f;
      __syncthreads();
      fr[tid] += d*prev;
      __syncthreads();
      d = d*d;
    }
  }

  // ---- linear interp 128 -> 32768 (align_corners=False) * noise ----
  {
    const float4* __restrict__ nz4 = (const float4*)(noise + (size_t)row*32768);
    float4* __restrict__ out4 = (float4*)(out + (size_t)row*32768);
    for (int n4 = tid; n4 < 8192; n4 += 128) {
      const float4 nz = nz4[n4];
      const int n = n4*4;
      float r[4];
      #pragma unroll
      for (int j=0;j<4;j++) {
        float pos = ((float)(n+j) + 0.5f) * (1.0f/256.0f) - 0.5f;
        pos = fminf(fmaxf(pos, 0.0f), 127.0f);
        const int i0 = (int)pos;            // floor (pos >= 0)
        const int i1 = min(i0+1, 127);
        const float w = pos - (float)i0;
        r[j] = fr[i0]*(1.0f-w) + fr[i1]*w;
      }
      float4 o;
      o.x = r[0]*nz.x; o.y = r[1]*nz.y; o.z = r[2]*nz.z; o.w = r[3]*nz.w;
      out4[n4] = o;
    }
  }
}

extern "C" void kernel_launch(void* const* d_in, const int* in_sizes, int n_in,
                              void* d_out, int out_size, void* d_ws, size_t ws_size,
                              hipStream_t stream)
{
  const float* x    = (const float*)d_in[0];
  const float* noise= (const float*)d_in[1];
  const float* Wup  = (const float*)d_in[2];
  const float* bup  = (const float*)d_in[3];
  const float* Wd0  = (const float*)d_in[4];
  const float* bd0  = (const float*)d_in[5];
  const float* Wd1  = (const float*)d_in[6];
  const float* bd1  = (const float*)d_in[7];
  const float* Wd2  = (const float*)d_in[8];
  const float* bd2  = (const float*)d_in[9];
  const float* Wdo  = (const float*)d_in[10];
  const float* bdo  = (const float*)d_in[11];
  const float* Wc0  = (const float*)d_in[12];
  const float* bc0  = (const float*)d_in[13];
  const float* Wc1  = (const float*)d_in[14];
  const float* bc1  = (const float*)d_in[15];
  const float* Wc2  = (const float*)d_in[16];
  const float* bc2  = (const float*)d_in[17];
  const float* Wc3  = (const float*)d_in[18];
  const float* bc3  = (const float*)d_in[19];
  float* out = (float*)d_out;

  hipLaunchKernelGGL(npg_fused, dim3(1024), dim3(128), 0, stream,
                     x, noise, Wup, bup, Wd0, bd0, Wd1, bd1, Wd2, bd2, Wdo, bdo,
                     Wc0, bc0, Wc1, bc1, Wc2, bc2, Wc3, bc3, out);
}

// Round 2
// 475.520 us; speedup vs baseline: 1.3229x; 1.3229x over previous
//
#include <hip/hip_runtime.h>

#define SLOPE 0.2f
__device__ __forceinline__ float lrelu(float v){ return v > 0.0f ? v : SLOPE*v; }

// ConvTranspose1d(k=4,s=2,p=1), 128->128 ch, input L (LDS), output 2L (LDS).
// Thread = (co = tid&127, q = tid>>7): computes output quarter t in
// [q*L/2, (q+1)*L/2) from inputs i in [q*L/4 - 1, q*L/4 + L/4].
// Tap map (x[i] contributes): w.z->t=2i, w.y->t=2i+1, w.x->t=2i+2, w.w->t=2i-1.
template<int L, bool RELU>
__device__ __forceinline__ void tconv_q(const float* __restrict__ W,
                                        const float* __restrict__ bias,
                                        const float* __restrict__ in,
                                        float* __restrict__ out,
                                        int co, int q)
{
  constexpr int TQ = L/2;   // outputs per thread
  constexpr int NI = L/4;   // interior inputs per thread
  const int i0 = q*NI;
  float acc[TQ];
  {
    const float b = bias[co];
    #pragma unroll
    for (int j=0;j<TQ;j++) acc[j]=b;
  }
  const bool hasM1 = (q > 0);   // wave-uniform
  const bool hasE  = (q < 3);
  #pragma unroll 2
  for (int ci=0; ci<128; ci++){
    const float4 w = *(const float4*)(W + ((size_t)ci*128 + co)*4);
    const float* xin = in + ci*L + i0;
    const float xm1 = hasM1 ? xin[-1] : 0.0f;   // i = i0-1 (dropped at i=-1)
    const float xE  = hasE  ? xin[NI] : 0.0f;   // i = i0+NI (dropped at i=L)
    float xv[NI];
    if constexpr (NI==2){ const float2 t=*(const float2*)xin; xv[0]=t.x; xv[1]=t.y; }
    else if constexpr (NI==4){ const float4 t=*(const float4*)xin;
      xv[0]=t.x; xv[1]=t.y; xv[2]=t.z; xv[3]=t.w; }
    else {
      const float4 t0=*(const float4*)xin; const float4 t1=*(const float4*)(xin+4);
      xv[0]=t0.x; xv[1]=t0.y; xv[2]=t0.z; xv[3]=t0.w;
      xv[4]=t1.x; xv[5]=t1.y; xv[6]=t1.z; xv[7]=t1.w;
    }
    acc[0]    += xm1*w.x;      // t = 2(i0-1)+2 = q*TQ
    acc[TQ-1] += xE *w.w;      // t = 2(i0+NI)-1 = q*TQ+TQ-1
    #pragma unroll
    for (int li=0; li<NI; li++){
      const float x = xv[li];
      acc[2*li]   += x*w.z;
      acc[2*li+1] += x*w.y;
      if (li<NI-1) acc[2*li+2] += x*w.x;   // li=NI-1 handled by next q's xm1
      if (li>0)    acc[2*li-1] += x*w.w;   // li=0 handled by prev q's xE
    }
  }
  float* op = out + co*(2*L) + q*TQ;
  #pragma unroll
  for (int j=0;j<TQ;j++) op[j] = RELU ? lrelu(acc[j]) : acc[j];
}

extern "C" __global__ __launch_bounds__(512, 6)
void npg_compute(const float* __restrict__ x,
                 const float* __restrict__ Wup, const float* __restrict__ bup,
                 const float* __restrict__ Wd0, const float* __restrict__ bd0,
                 const float* __restrict__ Wd1, const float* __restrict__ bd1,
                 const float* __restrict__ Wd2, const float* __restrict__ bd2,
                 const float* __restrict__ Wdo, const float* __restrict__ bdo,
                 const float* __restrict__ Wc0, const float* __restrict__ bc0,
                 const float* __restrict__ Wc1, const float* __restrict__ bc1,
                 const float* __restrict__ Wc2, const float* __restrict__ bc2,
                 const float* __restrict__ Wc3, const float* __restrict__ bc3,
                 float* __restrict__ frg)
{
  __shared__ float xrow[128];
  __shared__ float h0[128];
  __shared__ float h1[128];
  __shared__ float part[512];
  __shared__ float fr[128];
  __shared__ float bufA[128*32];   // 16 KB
  __shared__ float bufB[128*64];   // 32 KB
  __shared__ float sdecay;

  const int tid = threadIdx.x;
  const int row = blockIdx.x;
  const int c   = tid & 127;
  const int g   = tid >> 7;

  if (tid < 128) xrow[tid] = x[row*128 + tid];
  __syncthreads();

  // ---- decay head: 3x dense(128x128)+lrelu, 4-way ci split + LDS reduce ----
  {
    const float* inb = xrow;
    const float* Ws[3] = {Wd0, Wd1, Wd2};
    const float* bs[3] = {bd0, bd1, bd2};
    float* outs[3] = {h0, h1, h0};
    #pragma unroll
    for (int layer=0; layer<3; layer++){
      float a = 0.0f;
      const int base = g*32;
      const float* W = Ws[layer];
      #pragma unroll 8
      for (int i=0;i<32;i++) a += inb[base+i]*W[(size_t)(base+i)*128 + c];
      part[g*128 + c] = a;
      __syncthreads();
      if (tid < 128){
        const float v = part[tid]+part[128+tid]+part[256+tid]+part[384+tid] + bs[layer][tid];
        outs[layer][tid] = lrelu(v);
      }
      __syncthreads();
      inb = outs[layer];
    }
    if (tid < 128) part[tid] = h0[tid]*Wdo[tid];
    __syncthreads();
    if (tid < 64){
      float v = part[tid] + part[tid+64];
      #pragma unroll
      for (int off=32; off>0; off>>=1) v += __shfl_down(v, off, 64);
      if (tid==0){
        const float z = v + bdo[0];
        sdecay = 0.8f + 0.2f/(1.0f + expf(-z));
      }
    }
    __syncthreads();
  }

  // ---- up-linear: 1024 outputs, 2 per thread; bufA[o] = xf@Wup + bup ----
  {
    const int o = tid*2;
    float2 a = make_float2(bup[o], bup[o+1]);
    #pragma unroll 4
    for (int i=0;i<128;i++){
      const float xv = xrow[i];
      const float2 w = *(const float2*)(Wup + (size_t)i*1024 + o);
      a.x += xv*w.x; a.y += xv*w.y;
    }
    bufA[o] = a.x; bufA[o+1] = a.y;   // layout [co*8 + s]
    __syncthreads();
  }

  // ---- tconv chain: 8 -> 16 -> 32 -> 64 frames ----
  tconv_q<8 , true>(Wc0, bc0, bufA, bufB, c, g); __syncthreads();
  tconv_q<16, true>(Wc1, bc1, bufB, bufA, c, g); __syncthreads();
  tconv_q<32, true>(Wc2, bc2, bufA, bufB, c, g); __syncthreads();

  // ---- final tconv 128ch -> 1ch (64 -> 128), no lrelu; square; 4-way ci split ----
  {
    const int t = c;
    const bool even = ((t & 1) == 0);
    const int i  = t >> 1;
    const int ia = even ? (i-1) : i;
    const int ib = even ? i : (i+1);
    const float ma = (ia >= 0) ? 1.0f : 0.0f;
    const float mb = (ib < 64) ? 1.0f : 0.0f;
    const int iac = (ia >= 0) ? ia : 0;
    const int ibc = (ib < 64) ? ib : 63;
    float a = 0.0f;
    const int cb = g*32;
    #pragma unroll 4
    for (int k=0;k<32;k++){
      const int ci = cb + k;
      const float4 w = *(const float4*)(Wc3 + (size_t)ci*4);
      const float wa = even ? w.x : w.y;
      const float wb = even ? w.z : w.w;
      a += (bufB[ci*64 + iac]*ma)*wa + (bufB[ci*64 + ibc]*mb)*wb;
    }
    part[g*128 + t] = a;
    __syncthreads();
    if (tid < 128){
      const float s = part[tid]+part[128+tid]+part[256+tid]+part[384+tid] + bc3[0];
      fr[tid] = s*s;
    }
    __syncthreads();
  }

  // ---- weighted inclusive scan: v[t] = sum_{s<=t} decay^(t-s)*u[s] ----
  {
    float d = sdecay;
    #pragma unroll
    for (int o=1;o<128;o<<=1){
      const float prev = (tid < 128 && tid >= o) ? fr[tid-o] : 0.0f;
      __syncthreads();
      if (tid < 128) fr[tid] += d*prev;
      __syncthreads();
      d = d*d;
    }
  }

  if (tid < 128) frg[row*128 + tid] = fr[tid];
}

// ---- memory-bound: linear interp 128 -> 32768 (align_corners=False) * noise ----
extern "C" __global__ __launch_bounds__(256)
void npg_interp(const float* __restrict__ frg, const float* __restrict__ noise,
                float* __restrict__ out)
{
  __shared__ float fr[128];
  const int row = blockIdx.x >> 2;
  const int seg = blockIdx.x & 3;
  if (threadIdx.x < 128) fr[threadIdx.x] = frg[row*128 + threadIdx.x];
  __syncthreads();

  const float4* __restrict__ nz4 = (const float4*)(noise + (size_t)row*32768) + seg*2048;
  float4*       __restrict__ o4  = (float4*)(out   + (size_t)row*32768) + seg*2048;
  const int base_n = seg*8192;

  #pragma unroll 2
  for (int it=0; it<8; ++it){
    const int idx = it*256 + threadIdx.x;
    const float4 nz = nz4[idx];
    const int n = base_n + idx*4;
    float r[4];
    #pragma unroll
    for (int j=0;j<4;j++){
      float pos = ((float)(n+j) + 0.5f) * (1.0f/256.0f) - 0.5f;
      pos = fminf(fmaxf(pos, 0.0f), 127.0f);
      const int i0 = (int)pos;
      const int i1 = min(i0+1, 127);
      const float w = pos - (float)i0;
      r[j] = fr[i0]*(1.0f-w) + fr[i1]*w;
    }
    float4 o;
    o.x = r[0]*nz.x; o.y = r[1]*nz.y; o.z = r[2]*nz.z; o.w = r[3]*nz.w;
    o4[idx] = o;
  }
}

extern "C" void kernel_launch(void* const* d_in, const int* in_sizes, int n_in,
                              void* d_out, int out_size, void* d_ws, size_t ws_size,
                              hipStream_t stream)
{
  const float* x    = (const float*)d_in[0];
  const float* noise= (const float*)d_in[1];
  const float* Wup  = (const float*)d_in[2];
  const float* bup  = (const float*)d_in[3];
  const float* Wd0  = (const float*)d_in[4];
  const float* bd0  = (const float*)d_in[5];
  const float* Wd1  = (const float*)d_in[6];
  const float* bd1  = (const float*)d_in[7];
  const float* Wd2  = (const float*)d_in[8];
  const float* bd2  = (const float*)d_in[9];
  const float* Wdo  = (const float*)d_in[10];
  const float* bdo  = (const float*)d_in[11];
  const float* Wc0  = (const float*)d_in[12];
  const float* bc0  = (const float*)d_in[13];
  const float* Wc1  = (const float*)d_in[14];
  const float* bc1  = (const float*)d_in[15];
  const float* Wc2  = (const float*)d_in[16];
  const float* bc2  = (const float*)d_in[17];
  const float* Wc3  = (const float*)d_in[18];
  const float* bc3  = (const float*)d_in[19];
  float* out = (float*)d_out;
  float* frg = (float*)d_ws;   // 1024*128*4 = 512 KB scratch

  hipLaunchKernelGGL(npg_compute, dim3(1024), dim3(512), 0, stream,
                     x, Wup, bup, Wd0, bd0, Wd1, bd1, Wd2, bd2, Wdo, bdo,
                     Wc0, bc0, Wc1, bc1, Wc2, bc2, Wc3, bc3, frg);
  hipLaunchKernelGGL(npg_interp, dim3(4096), dim3(256), 0, stream,
                     frg, noise, out);
}